// Round 1
// 256.396 us; speedup vs baseline: 1.1056x; 1.1056x over previous
//
#include <hip/hip_runtime.h>

#define B_ 4
#define W_ 2048
#define C_ 1024
#define NH 16
#define KH 64

typedef __attribute__((ext_vector_type(8))) short short8;
typedef __attribute__((ext_vector_type(4))) short s16x4;
typedef __attribute__((ext_vector_type(4))) float f32x4;

__device__ __forceinline__ short f2bf(float f) {
    unsigned u = __builtin_bit_cast(unsigned, f);
    u = (u + 0x7FFFu + ((u >> 16) & 1u)) >> 16;
    return (short)u;
}
__device__ __forceinline__ float bf2f(short h) {
    return __builtin_bit_cast(float, ((unsigned)(unsigned short)h) << 16);
}

// ---------------- metric[n] = P[n] @ P[n]^T ----------------
__global__ __launch_bounds__(256) void k_metric(const float* __restrict__ P, float* __restrict__ M) {
    int n = blockIdx.x;
    __shared__ float sP[KH * KH];
    __shared__ float sPt[KH * 65];
    const float* Pn = P + n * KH * KH;
    for (int i = threadIdx.x; i < KH * KH; i += 256) {
        float v = Pn[i];
        sP[i] = v;
        sPt[(i & 63) * 65 + (i >> 6)] = v;
    }
    __syncthreads();
    float* Mn = M + n * KH * KH;
    for (int e = threadIdx.x; e < KH * KH; e += 256) {
        int i = e >> 6, k = e & 63;
        float s = 0.f;
        #pragma unroll 8
        for (int j = 0; j < KH; ++j) s += sP[i * KH + j] * sPt[j * 65 + k];
        Mn[e] = s;
    }
}

// ---------------- Wq[n*64+jj][c] = 0.125 * sum_k M[n][k][jj] * Wp[n*64+k][c] ----------------
__global__ __launch_bounds__(256) void k_wq(const float* __restrict__ M, const float* __restrict__ Wp,
                                            short* __restrict__ Wq) {
    int n = blockIdx.y, cseg = blockIdx.x;
    __shared__ float sM[KH * KH];
    __shared__ float sW[KH * KH];
    for (int i = threadIdx.x; i < KH * KH; i += 256) {
        sM[i] = M[n * KH * KH + i];
        int r = i >> 6, c = i & 63;
        sW[i] = Wp[(n * KH + r) * C_ + cseg * KH + c];
    }
    __syncthreads();
    for (int e = threadIdx.x; e < KH * KH; e += 256) {
        int jj = e >> 6, c = e & 63;
        float s = 0.f;
        #pragma unroll 8
        for (int k = 0; k < KH; ++k) s += sM[k * KH + jj] * sW[k * KH + c];
        Wq[(n * KH + jj) * C_ + cseg * KH + c] = f2bf(s * 0.125f);   // fold 1/sqrt(K)
    }
}

// ---------------- Wf[o][n*64+k] = sum_j T[n][k][j] * Wm[o][n*64+j] ----------------
__global__ __launch_bounds__(256) void k_wf(const float* __restrict__ T, const float* __restrict__ Wm,
                                            short* __restrict__ Wf) {
    int n = blockIdx.y, oseg = blockIdx.x;
    __shared__ float sTt[KH * 65];
    __shared__ float sW[KH * KH];
    for (int i = threadIdx.x; i < KH * KH; i += 256) {
        sTt[(i & 63) * 65 + (i >> 6)] = T[n * KH * KH + i];
        int r = i >> 6, c = i & 63;
        sW[i] = Wm[(oseg * KH + r) * C_ + n * KH + c];
    }
    __syncthreads();
    for (int e = threadIdx.x; e < KH * KH; e += 256) {
        int r = e >> 6, k = e & 63;
        float s = 0.f;
        #pragma unroll 8
        for (int j = 0; j < KH; ++j) s += sTt[j * 65 + k] * sW[r * KH + j];
        Wf[(oseg * KH + r) * C_ + n * KH + k] = f2bf(s);
    }
}

// ---------------- fp32 -> bf16 convert ----------------
__global__ __launch_bounds__(256) void k_cvt(const float* __restrict__ src, short* __restrict__ dst, int n4) {
    int i = blockIdx.x * 256 + threadIdx.x;
    if (i < n4) {
        float4 v = ((const float4*)src)[i];
        short4 o;
        o.x = f2bf(v.x); o.y = f2bf(v.y); o.z = f2bf(v.z); o.w = f2bf(v.w);
        ((short4*)dst)[i] = o;
    }
}

// ---------------- Out[M][OC] = A[M][1024] @ Bw[OC][1024]^T ----------------
// m97-style: global_load_lds width=16 into unpadded LDS, k-chunk XOR swizzle on global side.
template <int OC, bool OUT_FP32>
__global__ __launch_bounds__(256) void k_gemm(const short* __restrict__ A, const short* __restrict__ Bw,
                                              void* __restrict__ Out) {
    __shared__ short As[128 * 64];
    __shared__ short Bs[128 * 64];
    int bm = blockIdx.y, bn = blockIdx.x;
    int t = threadIdx.x;
    int wave = t >> 6, lane = t & 63;
    int q = lane >> 4, c = lane & 15;
    int wy = wave >> 1, wx = wave & 1;
    f32x4 acc[4][4] = {};
    int xsw = (c & 7);                       // reader-side swizzle
    for (int k0 = 0; k0 < C_; k0 += 64) {
        __syncthreads();
        #pragma unroll
        for (int e = 0; e < 4; ++e) {
            int row = (e * 256 + t) >> 3;
            int ks = ((t & 7) ^ (row & 7)) * 8;          // swizzled k-chunk (global side)
            __builtin_amdgcn_global_load_lds(
                (const __attribute__((address_space(1))) void*)&A[(size_t)(bm * 128 + row) * C_ + k0 + ks],
                (__attribute__((address_space(3))) void*)&As[e * 2048 + wave * 512], 16, 0, 0);
            __builtin_amdgcn_global_load_lds(
                (const __attribute__((address_space(1))) void*)&Bw[(size_t)(bn * 128 + row) * C_ + k0 + ks],
                (__attribute__((address_space(3))) void*)&Bs[e * 2048 + wave * 512], 16, 0, 0);
        }
        __syncthreads();
        #pragma unroll
        for (int kk = 0; kk < 64; kk += 32) {
            int o = kk >> 3;                             // 0 or 4
            int xo = ((o + q) ^ xsw) * 8;
            short8 af[4], bfr[4];
            #pragma unroll
            for (int i = 0; i < 4; ++i)
                af[i] = *(const short8*)&As[(wy * 64 + i * 16 + c) * 64 + xo];
            #pragma unroll
            for (int j = 0; j < 4; ++j)
                bfr[j] = *(const short8*)&Bs[(wx * 64 + j * 16 + c) * 64 + xo];
            #pragma unroll
            for (int i = 0; i < 4; ++i)
                #pragma unroll
                for (int j = 0; j < 4; ++j)
                    acc[i][j] = __builtin_amdgcn_mfma_f32_16x16x32_bf16(af[i], bfr[j], acc[i][j], 0, 0, 0);
        }
    }
    #pragma unroll
    for (int i = 0; i < 4; ++i)
        #pragma unroll
        for (int j = 0; j < 4; ++j)
            #pragma unroll
            for (int r = 0; r < 4; ++r) {
                int row = bm * 128 + wy * 64 + i * 16 + q * 4 + r;
                int col = bn * 128 + wx * 64 + j * 16 + c;
                if (OUT_FP32) ((float*)Out)[(size_t)row * OC + col] = acc[i][j][r];
                else ((short*)Out)[(size_t)row * OC + col] = f2bf(acc[i][j][r]);
            }
}

// ---------------- k_outer: O_cc = P_cc^T @ P_cc per (b,n,cc), bf16 hi/lo into C slots ----------------
// Replaces the serial half of k_prefix: 1984 parallel blocks instead of 64 serial-loop blocks.
// Same verified fragment + [j][k] store layout as the old k_prefix (O symmetric).
__global__ __launch_bounds__(256) void k_outer(const short* __restrict__ pjqm,
                                               short* __restrict__ Chi, short* __restrict__ Clo) {
    int cc = blockIdx.x, n = blockIdx.y, b = blockIdx.z;   // cc in [0,31): O_31 is never consumed
    int bn = b * NH + n;
    int t = threadIdx.x, wave = t >> 6, lane = t & 63;
    int q = lane >> 4, c = lane & 15;
    __shared__ short Pt_s[64 * 72];   // P_cc^T  [k][v]
    #pragma unroll
    for (int e = 0; e < 2; ++e) {
        int chv = e * 256 + t, row = chv >> 3, sub = chv & 7;   // row = v
        short8 p8 = *(const short8*)&pjqm[(size_t)(b * W_ + cc * 64 + row) * 2048 + n * KH + sub * 8];
        #pragma unroll
        for (int j = 0; j < 8; ++j) Pt_s[(sub * 8 + j) * 72 + row] = p8[j];
    }
    __syncthreads();
    short8 a0 = *(const short8*)&Pt_s[(wave * 16 + c) * 72 + q * 8];
    short8 a1 = *(const short8*)&Pt_s[(wave * 16 + c) * 72 + 32 + q * 8];
    size_t cbase = ((size_t)bn * 32 + cc) * 4096;
    #pragma unroll
    for (int tj = 0; tj < 4; ++tj) {
        short8 b0 = *(const short8*)&Pt_s[(tj * 16 + c) * 72 + q * 8];
        short8 b1 = *(const short8*)&Pt_s[(tj * 16 + c) * 72 + 32 + q * 8];
        f32x4 acc = {};
        acc = __builtin_amdgcn_mfma_f32_16x16x32_bf16(a0, b0, acc, 0, 0, 0);
        acc = __builtin_amdgcn_mfma_f32_16x16x32_bf16(a1, b1, acc, 0, 0, 0);
        s16x4 hi, lo;
        #pragma unroll
        for (int r = 0; r < 4; ++r) {
            float a = acc[r];
            short h = f2bf(a);
            hi[r] = h;
            lo[r] = f2bf(a - bf2f(h));
        }
        size_t off = cbase + (size_t)(tj * 16 + c) * 64 + wave * 16 + q * 4;  // [j][k], sym
        *(s16x4*)&Chi[off] = hi;
        *(s16x4*)&Clo[off] = lo;
    }
}

// ---------------- k_scan: in-place exclusive prefix over the 32 chunk slots ----------------
// Each thread owns 4 of the 4096 elements for one (b,n); fp32 running sum in regs;
// read O_cc -> write C_cc (exclusive) to the SAME slot (per-thread program order = safe).
__global__ __launch_bounds__(256) void k_scan(short* __restrict__ Chi, short* __restrict__ Clo) {
    int bn = blockIdx.y;
    int el = blockIdx.x * 1024 + threadIdx.x * 4;
    size_t off = (size_t)bn * 32 * 4096 + el;
    float run[4] = {0.f, 0.f, 0.f, 0.f};
    s16x4 h = *(const s16x4*)&Chi[off];
    s16x4 l = *(const s16x4*)&Clo[off];
    for (int cc = 0; cc < 31; ++cc) {
        s16x4 nh, nl;
        if (cc < 30) {                      // one-deep prefetch of next chunk's O
            nh = *(const s16x4*)&Chi[off + 4096];
            nl = *(const s16x4*)&Clo[off + 4096];
        }
        s16x4 oh, ol;
        #pragma unroll
        for (int r = 0; r < 4; ++r) {
            float o = bf2f(h[r]) + bf2f(l[r]);
            float cv = run[r];
            short hh = f2bf(cv);
            oh[r] = hh;
            ol[r] = f2bf(cv - bf2f(hh));
            run[r] = cv + o;
        }
        *(s16x4*)&Chi[off] = oh;
        *(s16x4*)&Clo[off] = ol;
        h = nh; l = nl;
        off += 4096;
    }
    // cc = 31: pure write (slot never held a computed O)
    s16x4 oh, ol;
    #pragma unroll
    for (int r = 0; r < 4; ++r) {
        short hh = f2bf(run[r]);
        oh[r] = hh;
        ol[r] = f2bf(run[r] - bf2f(hh));
    }
    *(s16x4*)&Chi[off] = oh;
    *(s16x4*)&Clo[off] = ol;
}

// ---------------- k_chunk: nudged_c = causal_intra(QM_c,P_c) + QM_c @ (Chi+Clo) ----------------
// grid (32 chunk, 16 n, 4 b) x 256 thr (4 waves); one-shot, 32 MFMA/wave, 2 barriers.
__global__ __launch_bounds__(256) void k_chunk(const short* __restrict__ pjqm,
                                               const short* __restrict__ Chi, const short* __restrict__ Clo,
                                               short* __restrict__ Nd) {
    int cc = blockIdx.x, n = blockIdx.y, b = blockIdx.z;
    int t = threadIdx.x, wave = t >> 6, lane = t & 63;
    int q = lane >> 4, c = lane & 15;
    __shared__ short Ps[64 * 72];     // P_c   [v][k]
    __shared__ short Pt_s[64 * 72];   // P_c^T [k][v]
    __shared__ short Ch[64 * 72];     // C_hi  [j][k]
    __shared__ short Cl[64 * 72];     // C_lo  [j][k]
    __shared__ short St[4][16 * 72];  // per-wave S strip [w][v]
    int w0g = b * W_ + cc * 64;

    // QM rows for this wave (dual-use: B-frag in QK, A-frag in QM@C).
    const short* qmrow = &pjqm[(size_t)(w0g + wave * 16 + c) * 2048 + 1024 + n * KH];
    short8 bq0 = *(const short8*)(qmrow + q * 8);
    short8 bq1 = *(const short8*)(qmrow + 32 + q * 8);

    #pragma unroll
    for (int e = 0; e < 2; ++e) {
        int chv = e * 256 + t, row = chv >> 3, sub = chv & 7;
        short8 p8 = *(const short8*)&pjqm[(size_t)(w0g + row) * 2048 + n * KH + sub * 8];
        *(short8*)&Ps[row * 72 + sub * 8] = p8;
        #pragma unroll
        for (int j = 0; j < 8; ++j) Pt_s[(sub * 8 + j) * 72 + row] = p8[j];
        size_t cbase = ((size_t)((b * NH + n) * 32 + cc)) * 4096;
        *(short8*)&Ch[row * 72 + sub * 8] = *(const short8*)&Chi[cbase + row * 64 + sub * 8];
        *(short8*)&Cl[row * 72 + sub * 8] = *(const short8*)&Clo[cbase + row * 64 + sub * 8];
    }
    __syncthreads();
    // QK intra: S^T = P_c @ QM^T, masked v_loc > w_loc, packed to per-wave St strip
    #pragma unroll
    for (int ct = 0; ct < 4; ++ct) {
        short8 a0 = *(const short8*)&Ps[(ct * 16 + c) * 72 + q * 8];
        short8 a1 = *(const short8*)&Ps[(ct * 16 + c) * 72 + 32 + q * 8];
        f32x4 s = {};
        s = __builtin_amdgcn_mfma_f32_16x16x32_bf16(a0, bq0, s, 0, 0, 0);
        s = __builtin_amdgcn_mfma_f32_16x16x32_bf16(a1, bq1, s, 0, 0, 0);
        int vb = ct * 16 + q * 4, wl = wave * 16 + c;
        s16x4 pk;
        #pragma unroll
        for (int r = 0; r < 4; ++r) {
            float v = s[r];
            if (vb + r > wl) v = 0.f;
            pk[r] = f2bf(v);
        }
        *(s16x4*)&St[wave][c * 72 + ct * 16 + q * 4] = pk;
    }
    __syncthreads();                  // St visible (round-4 lesson: no barrier-free LDS RAW)
    // PV intra + QM @ C_hi + QM @ C_lo
    f32x4 oc[4] = {};
    short8 as0 = *(const short8*)&St[wave][c * 72 + q * 8];
    short8 as1 = *(const short8*)&St[wave][c * 72 + 32 + q * 8];
    #pragma unroll
    for (int tj = 0; tj < 4; ++tj) {
        short8 bp0 = *(const short8*)&Pt_s[(tj * 16 + c) * 72 + q * 8];
        short8 bp1 = *(const short8*)&Pt_s[(tj * 16 + c) * 72 + 32 + q * 8];
        oc[tj] = __builtin_amdgcn_mfma_f32_16x16x32_bf16(as0, bp0, oc[tj], 0, 0, 0);
        oc[tj] = __builtin_amdgcn_mfma_f32_16x16x32_bf16(as1, bp1, oc[tj], 0, 0, 0);
        short8 bh0 = *(const short8*)&Ch[(tj * 16 + c) * 72 + q * 8];
        short8 bh1 = *(const short8*)&Ch[(tj * 16 + c) * 72 + 32 + q * 8];
        oc[tj] = __builtin_amdgcn_mfma_f32_16x16x32_bf16(bq0, bh0, oc[tj], 0, 0, 0);
        oc[tj] = __builtin_amdgcn_mfma_f32_16x16x32_bf16(bq1, bh1, oc[tj], 0, 0, 0);
        short8 bl0 = *(const short8*)&Cl[(tj * 16 + c) * 72 + q * 8];
        short8 bl1 = *(const short8*)&Cl[(tj * 16 + c) * 72 + 32 + q * 8];
        oc[tj] = __builtin_amdgcn_mfma_f32_16x16x32_bf16(bq0, bl0, oc[tj], 0, 0, 0);
        oc[tj] = __builtin_amdgcn_mfma_f32_16x16x32_bf16(bq1, bl1, oc[tj], 0, 0, 0);
    }
    #pragma unroll
    for (int tj = 0; tj < 4; ++tj)
        #pragma unroll
        for (int r = 0; r < 4; ++r)
            Nd[(size_t)(w0g + wave * 16 + q * 4 + r) * C_ + n * KH + tj * 16 + c] = f2bf(oc[tj][r]);
}

extern "C" void kernel_launch(void* const* d_in, const int* in_sizes, int n_in,
                              void* d_out, int out_size, void* d_ws, size_t ws_size,
                              hipStream_t stream) {
    const float* x  = (const float*)d_in[0];
    const float* Wp = (const float*)d_in[1];
    const float* Pm = (const float*)d_in[2];
    const float* Tr = (const float*)d_in[3];
    const float* Wm = (const float*)d_in[4];
    float* out = (float*)d_out;
    char* ws = (char*)d_ws;

    const size_t MB = 1024 * 1024;
    float* metric = (float*)ws;                        // 256 KB
    short* wcat  = (short*)(ws + 256 * 1024);          // 4 MB: [Wp(1024) ; Wq(1024)] x 1024
    short* wp16  = wcat;
    short* wq16  = wcat + C_ * C_;
    short* wf16  = (short*)(ws + 256 * 1024 + 4 * MB); // 2 MB
    short* x16   = (short*)(ws + 256 * 1024 + 6 * MB); // 16 MB (aliased by nd16 later)
    short* pjqm  = (short*)(ws + 256 * 1024 + 22 * MB);// 32 MB: [8192][2048] = [proj | qm]
    short* nd16  = x16;                                // x16 dead after concat GEMM
    short* Chi   = (short*)d_out;                      // d_out as scratch: 16.75 MB
    short* Clo   = Chi + 8 * MB;                       // 16.75 MB (exactly fills d_out)

    k_metric<<<dim3(NH), dim3(256), 0, stream>>>(Pm, metric);
    k_wq<<<dim3(16, NH), dim3(256), 0, stream>>>(metric, Wp, wq16);
    k_wf<<<dim3(16, NH), dim3(256), 0, stream>>>(Tr, Wm, wf16);
    k_cvt<<<dim3(8192), dim3(256), 0, stream>>>(x, x16, (B_ * W_ * C_) / 4);
    k_cvt<<<dim3(1024), dim3(256), 0, stream>>>(Wp, wp16, (C_ * C_) / 4);

    k_gemm<2048, false><<<dim3(16, 64), dim3(256), 0, stream>>>(x16, wcat, (void*)pjqm);
    k_outer<<<dim3(31, NH, B_), dim3(256), 0, stream>>>(pjqm, Chi, Clo);
    k_scan<<<dim3(4, 64), dim3(256), 0, stream>>>(Chi, Clo);
    k_chunk<<<dim3(32, NH, B_), dim3(256), 0, stream>>>(pjqm, Chi, Clo, nd16);
    k_gemm<1024, true><<<dim3(8, 64), dim3(256), 0, stream>>>(nd16, wf16, (void*)out);
}

// Round 2
// 246.804 us; speedup vs baseline: 1.1486x; 1.0389x over previous
//
#include <hip/hip_runtime.h>

#define B_ 4
#define W_ 2048
#define C_ 1024
#define NH 16
#define KH 64

typedef __attribute__((ext_vector_type(8))) short short8;
typedef __attribute__((ext_vector_type(4))) short s16x4;
typedef __attribute__((ext_vector_type(4))) float f32x4;

__device__ __forceinline__ short f2bf(float f) {
    unsigned u = __builtin_bit_cast(unsigned, f);
    u = (u + 0x7FFFu + ((u >> 16) & 1u)) >> 16;
    return (short)u;
}
__device__ __forceinline__ float bf2f(short h) {
    return __builtin_bit_cast(float, ((unsigned)(unsigned short)h) << 16);
}

#define MFMA(a, b, cc) __builtin_amdgcn_mfma_f32_16x16x32_bf16(a, b, cc, 0, 0, 0)

// ---------------- metric[n] = P[n] @ P[n]^T ----------------
__global__ __launch_bounds__(256) void k_metric(const float* __restrict__ P, float* __restrict__ M) {
    int n = blockIdx.x;
    __shared__ float sP[KH * KH];
    __shared__ float sPt[KH * 65];
    const float* Pn = P + n * KH * KH;
    for (int i = threadIdx.x; i < KH * KH; i += 256) {
        float v = Pn[i];
        sP[i] = v;
        sPt[(i & 63) * 65 + (i >> 6)] = v;
    }
    __syncthreads();
    float* Mn = M + n * KH * KH;
    for (int e = threadIdx.x; e < KH * KH; e += 256) {
        int i = e >> 6, k = e & 63;
        float s = 0.f;
        #pragma unroll 8
        for (int j = 0; j < KH; ++j) s += sP[i * KH + j] * sPt[j * 65 + k];
        Mn[e] = s;
    }
}

// ---------------- Wq[n*64+jj][c] = 0.125 * sum_k M[n][k][jj] * Wp[n*64+k][c] ----------------
__global__ __launch_bounds__(256) void k_wq(const float* __restrict__ M, const float* __restrict__ Wp,
                                            short* __restrict__ Wq) {
    int n = blockIdx.y, cseg = blockIdx.x;
    __shared__ float sM[KH * KH];
    __shared__ float sW[KH * KH];
    for (int i = threadIdx.x; i < KH * KH; i += 256) {
        sM[i] = M[n * KH * KH + i];
        int r = i >> 6, c = i & 63;
        sW[i] = Wp[(n * KH + r) * C_ + cseg * KH + c];
    }
    __syncthreads();
    for (int e = threadIdx.x; e < KH * KH; e += 256) {
        int jj = e >> 6, c = e & 63;
        float s = 0.f;
        #pragma unroll 8
        for (int k = 0; k < KH; ++k) s += sM[k * KH + jj] * sW[k * KH + c];
        Wq[(n * KH + jj) * C_ + cseg * KH + c] = f2bf(s * 0.125f);   // fold 1/sqrt(K)
    }
}

// ---------------- Wf[o][n*64+k] = sum_j T[n][k][j] * Wm[o][n*64+j] ----------------
__global__ __launch_bounds__(256) void k_wf(const float* __restrict__ T, const float* __restrict__ Wm,
                                            short* __restrict__ Wf) {
    int n = blockIdx.y, oseg = blockIdx.x;
    __shared__ float sTt[KH * 65];
    __shared__ float sW[KH * KH];
    for (int i = threadIdx.x; i < KH * KH; i += 256) {
        sTt[(i & 63) * 65 + (i >> 6)] = T[n * KH * KH + i];
        int r = i >> 6, c = i & 63;
        sW[i] = Wm[(oseg * KH + r) * C_ + n * KH + c];
    }
    __syncthreads();
    for (int e = threadIdx.x; e < KH * KH; e += 256) {
        int r = e >> 6, k = e & 63;
        float s = 0.f;
        #pragma unroll 8
        for (int j = 0; j < KH; ++j) s += sTt[j * 65 + k] * sW[r * KH + j];
        Wf[(oseg * KH + r) * C_ + n * KH + k] = f2bf(s);
    }
}

// ---------------- fp32 -> bf16 convert ----------------
__global__ __launch_bounds__(256) void k_cvt(const float* __restrict__ src, short* __restrict__ dst, int n4) {
    int i = blockIdx.x * 256 + threadIdx.x;
    if (i < n4) {
        float4 v = ((const float4*)src)[i];
        short4 o;
        o.x = f2bf(v.x); o.y = f2bf(v.y); o.z = f2bf(v.z); o.w = f2bf(v.w);
        ((short4*)dst)[i] = o;
    }
}

// ---------------- 256x256-tile 8-phase GEMM (T2+T3+T4+T5+T1): Out[M][OC] = A @ Bw^T, bf16 out ----
// 8 waves (2M x 4N), BK=64, LDS = 2dbuf x 2half x {A,B} x 16KB = 128KB.
// Each group g (one K-tile) = 4 phases, quadrant (mh,nh) order (0,0)(0,1)(1,1)(1,0).
// Stage schedule (derived from half-tile free/consume analysis):
//   P1: (g+1, A-half1)  P2: (g+1, B-half0)   -> into dbuf (g+1)&1 (freed end of group g-1)
//   P3: (g+2, A-half0)  P4: (g+2, B-half1)   -> into dbuf g&1 (freed after P2/P3 of this group)
// vmcnt(4) once per group (before final barrier): leaves P3/P4's 2 half-tiles in flight.
// XOR k-chunk swizzle (proven in 128^2 kernel, bank-conflict 0): LDS[r][sub] = G[r][sub^(r&7)].
template <int OC>
__global__ __launch_bounds__(512, 2) void k_gemm256(const short* __restrict__ A, const short* __restrict__ Bw,
                                                    short* __restrict__ Out) {
    constexpr int NBX = OC / 256;
    constexpr int NT = C_ / 64;          // 16 K-tiles
    __shared__ short As[4 * 8192];       // [dbuf*2+half][128 rows][64]
    __shared__ short Bs[4 * 8192];
    int tid = threadIdx.x;
    int wave = tid >> 6, lane = tid & 63;
    int q = lane >> 4, c = lane & 15;
    int wm = wave >> 2, wn = wave & 3;
    // T1: bijective XCD swizzle (grid = NBX*32 blocks, %8 == 0)
    int id = blockIdx.x + blockIdx.y * NBX;
    int f = (id & 7) * (NBX * 32 / 8) + (id >> 3);
    int bm = f / NBX, bn = f % NBX;
    int A_B0 = bm * 256, Bw_B0 = bn * 256;

    // staging geometry: 2 x global_load_lds per thread per half-tile (128 rows x 64 cols x 2B)
    int r0 = tid >> 3, sub0 = tid & 7;
    int r1 = r0 + 64;
    int sc0 = (sub0 ^ (r0 & 7)) * 8;     // pre-swizzled global k-chunk
    int sc1 = (sub0 ^ (r1 & 7)) * 8;
    int dst0 = wave * 512;               // lds short offset (wave-uniform; HW adds lane*16B)
    int dst1 = 4096 + dst0;

#define STAGE(BUF, MAT, T, H)                                                                    \
    {                                                                                            \
        int _reg = (((T) & 1) * 2 + (H)) * 8192;                                                 \
        const short* _s = &MAT[(size_t)(MAT##_B0 + (H) * 128) * 1024 + (T) * 64];                \
        __builtin_amdgcn_global_load_lds(                                                        \
            (const __attribute__((address_space(1))) void*)&_s[(size_t)r0 * 1024 + sc0],         \
            (__attribute__((address_space(3))) void*)&BUF[_reg + dst0], 16, 0, 0);               \
        __builtin_amdgcn_global_load_lds(                                                        \
            (const __attribute__((address_space(1))) void*)&_s[(size_t)r1 * 1024 + sc1],         \
            (__attribute__((address_space(3))) void*)&BUF[_reg + dst1], 16, 0, 0);               \
    }

    // reader addressing: frag row in half-region, swizzled chunk
    int arow = (wm * 64 + c) * 64;
    int brow = (wn * 32 + c) * 64;
    int xk0 = ((0 + q) ^ (c & 7)) * 8;   // k-step 0 (chunks 0-3)
    int xk1 = ((4 + q) ^ (c & 7)) * 8;   // k-step 1 (chunks 4-7)

    f32x4 acc[2][2][4][2] = {};

    // prologue: tile0 full + tile1 A-half0, B-half1 (the halves groups don't stage for tile 1)
    STAGE(As, A, 0, 0) STAGE(As, A, 0, 1) STAGE(Bs, Bw, 0, 0) STAGE(Bs, Bw, 0, 1)
    STAGE(As, A, 1, 0) STAGE(Bs, Bw, 1, 1)
    asm volatile("s_waitcnt vmcnt(4)" ::: "memory");
    __builtin_amdgcn_s_barrier();

    for (int g = 0; g < NT; ++g) {
        int X = (g & 1) * 2 * 8192;      // dbuf base (half0); half1 = X + 8192
        short8 af[4][2], bf_[2][2];
        // ---- P1: quadrant (0,0) ----
        if (g + 1 < NT) STAGE(As, A, g + 1, 1);
        #pragma unroll
        for (int i = 0; i < 4; ++i) {
            af[i][0] = *(const short8*)&As[X + arow + i * 1024 + xk0];
            af[i][1] = *(const short8*)&As[X + arow + i * 1024 + xk1];
        }
        #pragma unroll
        for (int j = 0; j < 2; ++j) {
            bf_[j][0] = *(const short8*)&Bs[X + brow + j * 1024 + xk0];
            bf_[j][1] = *(const short8*)&Bs[X + brow + j * 1024 + xk1];
        }
        __builtin_amdgcn_s_barrier();
        __builtin_amdgcn_s_setprio(1);
        #pragma unroll
        for (int i = 0; i < 4; ++i)
            #pragma unroll
            for (int j = 0; j < 2; ++j) {
                acc[0][0][i][j] = MFMA(af[i][0], bf_[j][0], acc[0][0][i][j]);
                acc[0][0][i][j] = MFMA(af[i][1], bf_[j][1], acc[0][0][i][j]);
            }
        __builtin_amdgcn_s_setprio(0);
        __builtin_amdgcn_s_barrier();
        // ---- P2: quadrant (0,1) ----
        if (g + 1 < NT) STAGE(Bs, Bw, g + 1, 0);
        #pragma unroll
        for (int j = 0; j < 2; ++j) {
            bf_[j][0] = *(const short8*)&Bs[X + 8192 + brow + j * 1024 + xk0];
            bf_[j][1] = *(const short8*)&Bs[X + 8192 + brow + j * 1024 + xk1];
        }
        __builtin_amdgcn_s_barrier();
        __builtin_amdgcn_s_setprio(1);
        #pragma unroll
        for (int i = 0; i < 4; ++i)
            #pragma unroll
            for (int j = 0; j < 2; ++j) {
                acc[0][1][i][j] = MFMA(af[i][0], bf_[j][0], acc[0][1][i][j]);
                acc[0][1][i][j] = MFMA(af[i][1], bf_[j][1], acc[0][1][i][j]);
            }
        __builtin_amdgcn_s_setprio(0);
        __builtin_amdgcn_s_barrier();
        // ---- P3: quadrant (1,1) ----
        if (g + 2 < NT) STAGE(As, A, g + 2, 0);
        #pragma unroll
        for (int i = 0; i < 4; ++i) {
            af[i][0] = *(const short8*)&As[X + 8192 + arow + i * 1024 + xk0];
            af[i][1] = *(const short8*)&As[X + 8192 + arow + i * 1024 + xk1];
        }
        __builtin_amdgcn_s_barrier();
        __builtin_amdgcn_s_setprio(1);
        #pragma unroll
        for (int i = 0; i < 4; ++i)
            #pragma unroll
            for (int j = 0; j < 2; ++j) {
                acc[1][1][i][j] = MFMA(af[i][0], bf_[j][0], acc[1][1][i][j]);
                acc[1][1][i][j] = MFMA(af[i][1], bf_[j][1], acc[1][1][i][j]);
            }
        __builtin_amdgcn_s_setprio(0);
        __builtin_amdgcn_s_barrier();
        // ---- P4: quadrant (1,0) ----
        if (g + 2 < NT) STAGE(Bs, Bw, g + 2, 1);
        #pragma unroll
        for (int j = 0; j < 2; ++j) {
            bf_[j][0] = *(const short8*)&Bs[X + brow + j * 1024 + xk0];
            bf_[j][1] = *(const short8*)&Bs[X + brow + j * 1024 + xk1];
        }
        __builtin_amdgcn_s_barrier();
        __builtin_amdgcn_s_setprio(1);
        #pragma unroll
        for (int i = 0; i < 4; ++i)
            #pragma unroll
            for (int j = 0; j < 2; ++j) {
                acc[1][0][i][j] = MFMA(af[i][0], bf_[j][0], acc[1][0][i][j]);
                acc[1][0][i][j] = MFMA(af[i][1], bf_[j][1], acc[1][0][i][j]);
            }
        __builtin_amdgcn_s_setprio(0);
        if (g + 2 < NT) { asm volatile("s_waitcnt vmcnt(4)" ::: "memory"); }
        else            { asm volatile("s_waitcnt vmcnt(0)" ::: "memory"); }
        __builtin_amdgcn_s_barrier();
    }
#undef STAGE
    #pragma unroll
    for (int mh = 0; mh < 2; ++mh)
        #pragma unroll
        for (int nh = 0; nh < 2; ++nh)
            #pragma unroll
            for (int i = 0; i < 4; ++i)
                #pragma unroll
                for (int j = 0; j < 2; ++j)
                    #pragma unroll
                    for (int r = 0; r < 4; ++r) {
                        int row = A_B0 + mh * 128 + wm * 64 + i * 16 + q * 4 + r;
                        int col = Bw_B0 + nh * 128 + wn * 32 + j * 16 + c;
                        Out[(size_t)row * OC + col] = f2bf(acc[mh][nh][i][j][r]);
                    }
}

// ---------------- 128x128 m97-style GEMM (kept for OC=1024, fp32 out) ----------------
template <int OC, bool OUT_FP32>
__global__ __launch_bounds__(256) void k_gemm(const short* __restrict__ A, const short* __restrict__ Bw,
                                              void* __restrict__ Out) {
    __shared__ short As[128 * 64];
    __shared__ short Bs[128 * 64];
    // T1: bijective XCD swizzle (grid = (OC/128) * 64 blocks, %8 == 0)
    constexpr int NBX = OC / 128;
    int id = blockIdx.x + blockIdx.y * NBX;
    int fl = (id & 7) * (NBX * 64 / 8) + (id >> 3);
    int bm = fl / NBX, bn = fl % NBX;
    int t = threadIdx.x;
    int wave = t >> 6, lane = t & 63;
    int q = lane >> 4, c = lane & 15;
    int wy = wave >> 1, wx = wave & 1;
    f32x4 acc[4][4] = {};
    int xsw = (c & 7);                       // reader-side swizzle
    for (int k0 = 0; k0 < C_; k0 += 64) {
        __syncthreads();
        #pragma unroll
        for (int e = 0; e < 4; ++e) {
            int row = (e * 256 + t) >> 3;
            int ks = ((t & 7) ^ (row & 7)) * 8;          // swizzled k-chunk (global side)
            __builtin_amdgcn_global_load_lds(
                (const __attribute__((address_space(1))) void*)&A[(size_t)(bm * 128 + row) * C_ + k0 + ks],
                (__attribute__((address_space(3))) void*)&As[e * 2048 + wave * 512], 16, 0, 0);
            __builtin_amdgcn_global_load_lds(
                (const __attribute__((address_space(1))) void*)&Bw[(size_t)(bn * 128 + row) * C_ + k0 + ks],
                (__attribute__((address_space(3))) void*)&Bs[e * 2048 + wave * 512], 16, 0, 0);
        }
        __syncthreads();
        #pragma unroll
        for (int kk = 0; kk < 64; kk += 32) {
            int o = kk >> 3;                             // 0 or 4
            int xo = ((o + q) ^ xsw) * 8;
            short8 af[4], bfr[4];
            #pragma unroll
            for (int i = 0; i < 4; ++i)
                af[i] = *(const short8*)&As[(wy * 64 + i * 16 + c) * 64 + xo];
            #pragma unroll
            for (int j = 0; j < 4; ++j)
                bfr[j] = *(const short8*)&Bs[(wx * 64 + j * 16 + c) * 64 + xo];
            #pragma unroll
            for (int i = 0; i < 4; ++i)
                #pragma unroll
                for (int j = 0; j < 4; ++j)
                    acc[i][j] = MFMA(af[i], bfr[j], acc[i][j]);
        }
    }
    #pragma unroll
    for (int i = 0; i < 4; ++i)
        #pragma unroll
        for (int j = 0; j < 4; ++j)
            #pragma unroll
            for (int r = 0; r < 4; ++r) {
                int row = bm * 128 + wy * 64 + i * 16 + q * 4 + r;
                int col = bn * 128 + wx * 64 + j * 16 + c;
                if (OUT_FP32) ((float*)Out)[(size_t)row * OC + col] = acc[i][j][r];
                else ((short*)Out)[(size_t)row * OC + col] = f2bf(acc[i][j][r]);
            }
}

// ---------------- k_outer: O_cc = P_cc^T @ P_cc per (b,n,cc), bf16 hi/lo into C slots ----------------
__global__ __launch_bounds__(256) void k_outer(const short* __restrict__ pjqm,
                                               short* __restrict__ Chi, short* __restrict__ Clo) {
    int cc = blockIdx.x, n = blockIdx.y, b = blockIdx.z;   // cc in [0,31): O_31 is never consumed
    int bn = b * NH + n;
    int t = threadIdx.x, wave = t >> 6, lane = t & 63;
    int q = lane >> 4, c = lane & 15;
    __shared__ short Pt_s[64 * 72];   // P_cc^T  [k][v]
    #pragma unroll
    for (int e = 0; e < 2; ++e) {
        int chv = e * 256 + t, row = chv >> 3, sub = chv & 7;   // row = v
        short8 p8 = *(const short8*)&pjqm[(size_t)(b * W_ + cc * 64 + row) * 2048 + n * KH + sub * 8];
        #pragma unroll
        for (int j = 0; j < 8; ++j) Pt_s[(sub * 8 + j) * 72 + row] = p8[j];
    }
    __syncthreads();
    short8 a0 = *(const short8*)&Pt_s[(wave * 16 + c) * 72 + q * 8];
    short8 a1 = *(const short8*)&Pt_s[(wave * 16 + c) * 72 + 32 + q * 8];
    size_t cbase = ((size_t)bn * 32 + cc) * 4096;
    #pragma unroll
    for (int tj = 0; tj < 4; ++tj) {
        short8 b0 = *(const short8*)&Pt_s[(tj * 16 + c) * 72 + q * 8];
        short8 b1 = *(const short8*)&Pt_s[(tj * 16 + c) * 72 + 32 + q * 8];
        f32x4 acc = {};
        acc = MFMA(a0, b0, acc);
        acc = MFMA(a1, b1, acc);
        s16x4 hi, lo;
        #pragma unroll
        for (int r = 0; r < 4; ++r) {
            float a = acc[r];
            short h = f2bf(a);
            hi[r] = h;
            lo[r] = f2bf(a - bf2f(h));
        }
        size_t off = cbase + (size_t)(tj * 16 + c) * 64 + wave * 16 + q * 4;  // [j][k], sym
        *(s16x4*)&Chi[off] = hi;
        *(s16x4*)&Clo[off] = lo;
    }
}

// ---------------- k_scan: in-place exclusive prefix over the 32 chunk slots ----------------
__global__ __launch_bounds__(256) void k_scan(short* __restrict__ Chi, short* __restrict__ Clo) {
    int bn = blockIdx.y;
    int el = blockIdx.x * 1024 + threadIdx.x * 4;
    size_t off = (size_t)bn * 32 * 4096 + el;
    float run[4] = {0.f, 0.f, 0.f, 0.f};
    s16x4 h = *(const s16x4*)&Chi[off];
    s16x4 l = *(const s16x4*)&Clo[off];
    for (int cc = 0; cc < 31; ++cc) {
        s16x4 nh, nl;
        if (cc < 30) {                      // one-deep prefetch of next chunk's O
            nh = *(const s16x4*)&Chi[off + 4096];
            nl = *(const s16x4*)&Clo[off + 4096];
        }
        s16x4 oh, ol;
        #pragma unroll
        for (int r = 0; r < 4; ++r) {
            float o = bf2f(h[r]) + bf2f(l[r]);
            float cv = run[r];
            short hh = f2bf(cv);
            oh[r] = hh;
            ol[r] = f2bf(cv - bf2f(hh));
            run[r] = cv + o;
        }
        *(s16x4*)&Chi[off] = oh;
        *(s16x4*)&Clo[off] = ol;
        h = nh; l = nl;
        off += 4096;
    }
    s16x4 oh, ol;
    #pragma unroll
    for (int r = 0; r < 4; ++r) {
        short hh = f2bf(run[r]);
        oh[r] = hh;
        ol[r] = f2bf(run[r] - bf2f(hh));
    }
    *(s16x4*)&Chi[off] = oh;
    *(s16x4*)&Clo[off] = ol;
}

// ---------------- k_chunk: nudged_c = causal_intra(QM_c,P_c) + QM_c @ (Chi+Clo) ----------------
__global__ __launch_bounds__(256) void k_chunk(const short* __restrict__ pjqm,
                                               const short* __restrict__ Chi, const short* __restrict__ Clo,
                                               short* __restrict__ Nd) {
    int cc = blockIdx.x, n = blockIdx.y, b = blockIdx.z;
    int t = threadIdx.x, wave = t >> 6, lane = t & 63;
    int q = lane >> 4, c = lane & 15;
    __shared__ short Ps[64 * 72];     // P_c   [v][k]
    __shared__ short Pt_s[64 * 72];   // P_c^T [k][v]
    __shared__ short Ch[64 * 72];     // C_hi  [j][k]
    __shared__ short Cl[64 * 72];     // C_lo  [j][k]
    __shared__ short St[4][16 * 72];  // per-wave S strip [w][v]
    int w0g = b * W_ + cc * 64;

    const short* qmrow = &pjqm[(size_t)(w0g + wave * 16 + c) * 2048 + 1024 + n * KH];
    short8 bq0 = *(const short8*)(qmrow + q * 8);
    short8 bq1 = *(const short8*)(qmrow + 32 + q * 8);

    #pragma unroll
    for (int e = 0; e < 2; ++e) {
        int chv = e * 256 + t, row = chv >> 3, sub = chv & 7;
        short8 p8 = *(const short8*)&pjqm[(size_t)(w0g + row) * 2048 + n * KH + sub * 8];
        *(short8*)&Ps[row * 72 + sub * 8] = p8;
        #pragma unroll
        for (int j = 0; j < 8; ++j) Pt_s[(sub * 8 + j) * 72 + row] = p8[j];
        size_t cbase = ((size_t)((b * NH + n) * 32 + cc)) * 4096;
        *(short8*)&Ch[row * 72 + sub * 8] = *(const short8*)&Chi[cbase + row * 64 + sub * 8];
        *(short8*)&Cl[row * 72 + sub * 8] = *(const short8*)&Clo[cbase + row * 64 + sub * 8];
    }
    __syncthreads();
    #pragma unroll
    for (int ct = 0; ct < 4; ++ct) {
        short8 a0 = *(const short8*)&Ps[(ct * 16 + c) * 72 + q * 8];
        short8 a1 = *(const short8*)&Ps[(ct * 16 + c) * 72 + 32 + q * 8];
        f32x4 s = {};
        s = MFMA(a0, bq0, s);
        s = MFMA(a1, bq1, s);
        int vb = ct * 16 + q * 4, wl = wave * 16 + c;
        s16x4 pk;
        #pragma unroll
        for (int r = 0; r < 4; ++r) {
            float v = s[r];
            if (vb + r > wl) v = 0.f;
            pk[r] = f2bf(v);
        }
        *(s16x4*)&St[wave][c * 72 + ct * 16 + q * 4] = pk;
    }
    __syncthreads();
    f32x4 oc[4] = {};
    short8 as0 = *(const short8*)&St[wave][c * 72 + q * 8];
    short8 as1 = *(const short8*)&St[wave][c * 72 + 32 + q * 8];
    #pragma unroll
    for (int tj = 0; tj < 4; ++tj) {
        short8 bp0 = *(const short8*)&Pt_s[(tj * 16 + c) * 72 + q * 8];
        short8 bp1 = *(const short8*)&Pt_s[(tj * 16 + c) * 72 + 32 + q * 8];
        oc[tj] = MFMA(as0, bp0, oc[tj]);
        oc[tj] = MFMA(as1, bp1, oc[tj]);
        short8 bh0 = *(const short8*)&Ch[(tj * 16 + c) * 72 + q * 8];
        short8 bh1 = *(const short8*)&Ch[(tj * 16 + c) * 72 + 32 + q * 8];
        oc[tj] = MFMA(bq0, bh0, oc[tj]);
        oc[tj] = MFMA(bq1, bh1, oc[tj]);
        short8 bl0 = *(const short8*)&Cl[(tj * 16 + c) * 72 + q * 8];
        short8 bl1 = *(const short8*)&Cl[(tj * 16 + c) * 72 + 32 + q * 8];
        oc[tj] = MFMA(bq0, bl0, oc[tj]);
        oc[tj] = MFMA(bq1, bl1, oc[tj]);
    }
    #pragma unroll
    for (int tj = 0; tj < 4; ++tj)
        #pragma unroll
        for (int r = 0; r < 4; ++r)
            Nd[(size_t)(w0g + wave * 16 + q * 4 + r) * C_ + n * KH + tj * 16 + c] = f2bf(oc[tj][r]);
}

extern "C" void kernel_launch(void* const* d_in, const int* in_sizes, int n_in,
                              void* d_out, int out_size, void* d_ws, size_t ws_size,
                              hipStream_t stream) {
    const float* x  = (const float*)d_in[0];
    const float* Wp = (const float*)d_in[1];
    const float* Pm = (const float*)d_in[2];
    const float* Tr = (const float*)d_in[3];
    const float* Wm = (const float*)d_in[4];
    float* out = (float*)d_out;
    char* ws = (char*)d_ws;

    const size_t MB = 1024 * 1024;
    float* metric = (float*)ws;                        // 256 KB
    short* wcat  = (short*)(ws + 256 * 1024);          // 4 MB: [Wp(1024) ; Wq(1024)] x 1024
    short* wp16  = wcat;
    short* wq16  = wcat + C_ * C_;
    short* wf16  = (short*)(ws + 256 * 1024 + 4 * MB); // 2 MB
    short* x16   = (short*)(ws + 256 * 1024 + 6 * MB); // 16 MB (aliased by nd16 later)
    short* pjqm  = (short*)(ws + 256 * 1024 + 22 * MB);// 32 MB: [8192][2048] = [proj | qm]
    short* nd16  = x16;                                // x16 dead after concat GEMM
    short* Chi   = (short*)d_out;                      // d_out as scratch: 16.75 MB
    short* Clo   = Chi + 8 * MB;                       // 16.75 MB (exactly fills d_out)

    k_metric<<<dim3(NH), dim3(256), 0, stream>>>(Pm, metric);
    k_wq<<<dim3(16, NH), dim3(256), 0, stream>>>(metric, Wp, wq16);
    k_wf<<<dim3(16, NH), dim3(256), 0, stream>>>(Tr, Wm, wf16);
    k_cvt<<<dim3(8192), dim3(256), 0, stream>>>(x, x16, (B_ * W_ * C_) / 4);
    k_cvt<<<dim3(1024), dim3(256), 0, stream>>>(Wp, wp16, (C_ * C_) / 4);

    k_gemm256<2048><<<dim3(8, 32), dim3(512), 0, stream>>>(x16, wcat, pjqm);
    k_outer<<<dim3(31, NH, B_), dim3(256), 0, stream>>>(pjqm, Chi, Clo);
    k_scan<<<dim3(4, 64), dim3(256), 0, stream>>>(Chi, Clo);
    k_chunk<<<dim3(32, NH, B_), dim3(256), 0, stream>>>(pjqm, Chi, Clo, nd16);
    k_gemm<1024, true><<<dim3(8, 64), dim3(256), 0, stream>>>(nd16, wf16, (void*)out);
}

// Round 3
// 246.406 us; speedup vs baseline: 1.1505x; 1.0016x over previous
//
#include <hip/hip_runtime.h>

#define B_ 4
#define W_ 2048
#define C_ 1024
#define NH 16
#define KH 64

typedef __attribute__((ext_vector_type(8))) short short8;
typedef __attribute__((ext_vector_type(4))) short s16x4;
typedef __attribute__((ext_vector_type(4))) float f32x4;

__device__ __forceinline__ short f2bf(float f) {
    unsigned u = __builtin_bit_cast(unsigned, f);
    u = (u + 0x7FFFu + ((u >> 16) & 1u)) >> 16;
    return (short)u;
}
__device__ __forceinline__ float bf2f(short h) {
    return __builtin_bit_cast(float, ((unsigned)(unsigned short)h) << 16);
}

#define MFMA(a, b, cc) __builtin_amdgcn_mfma_f32_16x16x32_bf16(a, b, cc, 0, 0, 0)

// ---------------- metric[n] = P[n] @ P[n]^T ----------------
__global__ __launch_bounds__(256) void k_metric(const float* __restrict__ P, float* __restrict__ M) {
    int n = blockIdx.x;
    __shared__ float sP[KH * KH];
    __shared__ float sPt[KH * 65];
    const float* Pn = P + n * KH * KH;
    for (int i = threadIdx.x; i < KH * KH; i += 256) {
        float v = Pn[i];
        sP[i] = v;
        sPt[(i & 63) * 65 + (i >> 6)] = v;
    }
    __syncthreads();
    float* Mn = M + n * KH * KH;
    for (int e = threadIdx.x; e < KH * KH; e += 256) {
        int i = e >> 6, k = e & 63;
        float s = 0.f;
        #pragma unroll 8
        for (int j = 0; j < KH; ++j) s += sP[i * KH + j] * sPt[j * 65 + k];
        Mn[e] = s;
    }
}

// ---------------- Wq[n*64+jj][c] = 0.125 * sum_k M[n][k][jj] * Wp[n*64+k][c] ----------------
__global__ __launch_bounds__(256) void k_wq(const float* __restrict__ M, const float* __restrict__ Wp,
                                            short* __restrict__ Wq) {
    int n = blockIdx.y, cseg = blockIdx.x;
    __shared__ float sM[KH * KH];
    __shared__ float sW[KH * KH];
    for (int i = threadIdx.x; i < KH * KH; i += 256) {
        sM[i] = M[n * KH * KH + i];
        int r = i >> 6, c = i & 63;
        sW[i] = Wp[(n * KH + r) * C_ + cseg * KH + c];
    }
    __syncthreads();
    for (int e = threadIdx.x; e < KH * KH; e += 256) {
        int jj = e >> 6, c = e & 63;
        float s = 0.f;
        #pragma unroll 8
        for (int k = 0; k < KH; ++k) s += sM[k * KH + jj] * sW[k * KH + c];
        Wq[(n * KH + jj) * C_ + cseg * KH + c] = f2bf(s * 0.125f);   // fold 1/sqrt(K)
    }
}

// ---------------- Wf[o][n*64+k] = sum_j T[n][k][j] * Wm[o][n*64+j] ----------------
__global__ __launch_bounds__(256) void k_wf(const float* __restrict__ T, const float* __restrict__ Wm,
                                            short* __restrict__ Wf) {
    int n = blockIdx.y, oseg = blockIdx.x;
    __shared__ float sTt[KH * 65];
    __shared__ float sW[KH * KH];
    for (int i = threadIdx.x; i < KH * KH; i += 256) {
        sTt[(i & 63) * 65 + (i >> 6)] = T[n * KH * KH + i];
        int r = i >> 6, c = i & 63;
        sW[i] = Wm[(oseg * KH + r) * C_ + n * KH + c];
    }
    __syncthreads();
    for (int e = threadIdx.x; e < KH * KH; e += 256) {
        int r = e >> 6, k = e & 63;
        float s = 0.f;
        #pragma unroll 8
        for (int j = 0; j < KH; ++j) s += sTt[j * 65 + k] * sW[r * KH + j];
        Wf[(oseg * KH + r) * C_ + n * KH + k] = f2bf(s);
    }
}

// ---------------- fp32 -> bf16 convert ----------------
__global__ __launch_bounds__(256) void k_cvt(const float* __restrict__ src, short* __restrict__ dst, int n4) {
    int i = blockIdx.x * 256 + threadIdx.x;
    if (i < n4) {
        float4 v = ((const float4*)src)[i];
        short4 o;
        o.x = f2bf(v.x); o.y = f2bf(v.y); o.z = f2bf(v.z); o.w = f2bf(v.w);
        ((short4*)dst)[i] = o;
    }
}

// ---------------- 256x256-tile 8-phase GEMM: Out[M][OC] = A @ Bw^T, bf16 out ----------------
// 8 waves (2M x 4N), BK=64, LDS = 2dbuf x 2half x {A,B} x 16KB = 128KB.
// Quadrant order (0,0)(0,1)(1,1)(1,0) with register reuse:
//   P1 ds-reads af0(A-h0)+bf0(B-h0); P2 only bf1(B-h1); P3 only af1(A-h1); P4 re-reads bf0.
// LDS halves free one per phase -> stage schedule (group g):
//   P1: B(g+1,h0)  [4-phase window; B panel is L2-resident so ~200-400cy latency OK]
//   P2: A(g+2,h0)  P3: B(g+2,h1)  P4: A(g+2,h1)   [7-phase windows; covers HBM ~900cy]
// Single vmcnt(6) per group (3 half-tiles in flight, never drain to 0 mid-loop).
// XOR k-chunk swizzle on global source side; LDS linear (global_load_lds constraint).
template <int OC>
__global__ __launch_bounds__(512, 2) void k_gemm256(const short* __restrict__ A, const short* __restrict__ Bw,
                                                    short* __restrict__ Out) {
    constexpr int NBX = OC / 256;
    constexpr int NT = C_ / 64;          // 16 K-tiles
    __shared__ short As[4 * 8192];       // [dbuf*2+half][128 rows][64]
    __shared__ short Bs[4 * 8192];
    int tid = threadIdx.x;
    int wave = tid >> 6, lane = tid & 63;
    int q = lane >> 4, c = lane & 15;
    int wm = wave >> 2, wn = wave & 3;
    // T1: bijective XCD swizzle (grid = NBX*32 blocks, %8 == 0)
    int id = blockIdx.x + blockIdx.y * NBX;
    int f = (id & 7) * (NBX * 32 / 8) + (id >> 3);
    int bm = f / NBX, bn = f % NBX;
    int A_B0 = bm * 256, Bw_B0 = bn * 256;

    // staging geometry: 2 x global_load_lds per thread per half-tile (128 rows x 64 cols x 2B)
    int r0 = tid >> 3, sub0 = tid & 7;
    int r1 = r0 + 64;
    int sc0 = (sub0 ^ (r0 & 7)) * 8;     // pre-swizzled global k-chunk
    int sc1 = (sub0 ^ (r1 & 7)) * 8;
    int dst0 = wave * 512;               // lds short offset (wave-uniform; HW adds lane*16B)
    int dst1 = 4096 + dst0;

#define STAGE(BUF, MAT, T, H)                                                                    \
    {                                                                                            \
        int _reg = (((T) & 1) * 2 + (H)) * 8192;                                                 \
        const short* _s = &MAT[(size_t)(MAT##_B0 + (H) * 128) * 1024 + (T) * 64];                \
        __builtin_amdgcn_global_load_lds(                                                        \
            (const __attribute__((address_space(1))) void*)&_s[(size_t)r0 * 1024 + sc0],         \
            (__attribute__((address_space(3))) void*)&BUF[_reg + dst0], 16, 0, 0);               \
        __builtin_amdgcn_global_load_lds(                                                        \
            (const __attribute__((address_space(1))) void*)&_s[(size_t)r1 * 1024 + sc1],         \
            (__attribute__((address_space(3))) void*)&BUF[_reg + dst1], 16, 0, 0);               \
    }

    // reader addressing: frag row in half-region, swizzled chunk
    int arow = (wm * 64 + c) * 64;
    int brow = (wn * 32 + c) * 64;
    int xk0 = ((0 + q) ^ (c & 7)) * 8;   // k-step 0 (chunks 0-3)
    int xk1 = ((4 + q) ^ (c & 7)) * 8;   // k-step 1 (chunks 4-7)

    f32x4 acc[2][2][4][2] = {};

    // prologue: tile0 full, then tile1's {A-h0, B-h1, A-h1} (issue order = steady-state P2,P3,P4)
    STAGE(As, A, 0, 0) STAGE(As, A, 0, 1) STAGE(Bs, Bw, 0, 0) STAGE(Bs, Bw, 0, 1)
    STAGE(As, A, 1, 0) STAGE(Bs, Bw, 1, 1) STAGE(As, A, 1, 1)
    asm volatile("s_waitcnt vmcnt(6)" ::: "memory");
    __builtin_amdgcn_s_barrier();

    for (int g = 0; g < NT; ++g) {
        int X = (g & 1) * 16384;         // dbuf base (half0); half1 = X + 8192
        short8 af0[4][2], af1[4][2], bf0[2][2], bf1[2][2];
        // ---- P1: quadrant (0,0) : read af0, bf0 ----
        if (g + 1 < NT) STAGE(Bs, Bw, g + 1, 0);
        #pragma unroll
        for (int i = 0; i < 4; ++i) {
            af0[i][0] = *(const short8*)&As[X + arow + i * 1024 + xk0];
            af0[i][1] = *(const short8*)&As[X + arow + i * 1024 + xk1];
        }
        #pragma unroll
        for (int j = 0; j < 2; ++j) {
            bf0[j][0] = *(const short8*)&Bs[X + brow + j * 1024 + xk0];
            bf0[j][1] = *(const short8*)&Bs[X + brow + j * 1024 + xk1];
        }
        __builtin_amdgcn_s_barrier();
        __builtin_amdgcn_s_setprio(1);
        #pragma unroll
        for (int i = 0; i < 4; ++i)
            #pragma unroll
            for (int j = 0; j < 2; ++j) {
                acc[0][0][i][j] = MFMA(af0[i][0], bf0[j][0], acc[0][0][i][j]);
                acc[0][0][i][j] = MFMA(af0[i][1], bf0[j][1], acc[0][0][i][j]);
            }
        __builtin_amdgcn_s_setprio(0);
        __builtin_amdgcn_s_barrier();
        // ---- P2: quadrant (0,1) : read bf1, reuse af0 ----
        if (g + 2 < NT) STAGE(As, A, g + 2, 0);
        #pragma unroll
        for (int j = 0; j < 2; ++j) {
            bf1[j][0] = *(const short8*)&Bs[X + 8192 + brow + j * 1024 + xk0];
            bf1[j][1] = *(const short8*)&Bs[X + 8192 + brow + j * 1024 + xk1];
        }
        __builtin_amdgcn_s_barrier();
        __builtin_amdgcn_s_setprio(1);
        #pragma unroll
        for (int i = 0; i < 4; ++i)
            #pragma unroll
            for (int j = 0; j < 2; ++j) {
                acc[0][1][i][j] = MFMA(af0[i][0], bf1[j][0], acc[0][1][i][j]);
                acc[0][1][i][j] = MFMA(af0[i][1], bf1[j][1], acc[0][1][i][j]);
            }
        __builtin_amdgcn_s_setprio(0);
        __builtin_amdgcn_s_barrier();
        // ---- P3: quadrant (1,1) : read af1, reuse bf1 ----
        if (g + 2 < NT) STAGE(Bs, Bw, g + 2, 1);
        #pragma unroll
        for (int i = 0; i < 4; ++i) {
            af1[i][0] = *(const short8*)&As[X + 8192 + arow + i * 1024 + xk0];
            af1[i][1] = *(const short8*)&As[X + 8192 + arow + i * 1024 + xk1];
        }
        __builtin_amdgcn_s_barrier();
        __builtin_amdgcn_s_setprio(1);
        #pragma unroll
        for (int i = 0; i < 4; ++i)
            #pragma unroll
            for (int j = 0; j < 2; ++j) {
                acc[1][1][i][j] = MFMA(af1[i][0], bf1[j][0], acc[1][1][i][j]);
                acc[1][1][i][j] = MFMA(af1[i][1], bf1[j][1], acc[1][1][i][j]);
            }
        __builtin_amdgcn_s_setprio(0);
        __builtin_amdgcn_s_barrier();
        // ---- P4: quadrant (1,0) : re-read bf0, reuse af1 ----
        if (g + 2 < NT) STAGE(As, A, g + 2, 1);
        #pragma unroll
        for (int j = 0; j < 2; ++j) {
            bf0[j][0] = *(const short8*)&Bs[X + brow + j * 1024 + xk0];
            bf0[j][1] = *(const short8*)&Bs[X + brow + j * 1024 + xk1];
        }
        __builtin_amdgcn_s_barrier();
        __builtin_amdgcn_s_setprio(1);
        #pragma unroll
        for (int i = 0; i < 4; ++i)
            #pragma unroll
            for (int j = 0; j < 2; ++j) {
                acc[1][0][i][j] = MFMA(af1[i][0], bf0[j][0], acc[1][0][i][j]);
                acc[1][0][i][j] = MFMA(af1[i][1], bf0[j][1], acc[1][0][i][j]);
            }
        __builtin_amdgcn_s_setprio(0);
        if (g < NT - 2) { asm volatile("s_waitcnt vmcnt(6)" ::: "memory"); }
        else            { asm volatile("s_waitcnt vmcnt(0)" ::: "memory"); }
        __builtin_amdgcn_s_barrier();
    }
#undef STAGE
    #pragma unroll
    for (int mh = 0; mh < 2; ++mh)
        #pragma unroll
        for (int nh = 0; nh < 2; ++nh)
            #pragma unroll
            for (int i = 0; i < 4; ++i)
                #pragma unroll
                for (int j = 0; j < 2; ++j)
                    #pragma unroll
                    for (int r = 0; r < 4; ++r) {
                        int row = A_B0 + mh * 128 + wm * 64 + i * 16 + q * 4 + r;
                        int col = Bw_B0 + nh * 128 + wn * 32 + j * 16 + c;
                        Out[(size_t)row * OC + col] = f2bf(acc[mh][nh][i][j][r]);
                    }
}

// ---------------- 128x128 m97-style GEMM (kept for OC=1024, fp32 out) ----------------
template <int OC, bool OUT_FP32>
__global__ __launch_bounds__(256) void k_gemm(const short* __restrict__ A, const short* __restrict__ Bw,
                                              void* __restrict__ Out) {
    __shared__ short As[128 * 64];
    __shared__ short Bs[128 * 64];
    // T1: bijective XCD swizzle (grid = (OC/128) * 64 blocks, %8 == 0)
    constexpr int NBX = OC / 128;
    int id = blockIdx.x + blockIdx.y * NBX;
    int fl = (id & 7) * (NBX * 64 / 8) + (id >> 3);
    int bm = fl / NBX, bn = fl % NBX;
    int t = threadIdx.x;
    int wave = t >> 6, lane = t & 63;
    int q = lane >> 4, c = lane & 15;
    int wy = wave >> 1, wx = wave & 1;
    f32x4 acc[4][4] = {};
    int xsw = (c & 7);                       // reader-side swizzle
    for (int k0 = 0; k0 < C_; k0 += 64) {
        __syncthreads();
        #pragma unroll
        for (int e = 0; e < 4; ++e) {
            int row = (e * 256 + t) >> 3;
            int ks = ((t & 7) ^ (row & 7)) * 8;          // swizzled k-chunk (global side)
            __builtin_amdgcn_global_load_lds(
                (const __attribute__((address_space(1))) void*)&A[(size_t)(bm * 128 + row) * C_ + k0 + ks],
                (__attribute__((address_space(3))) void*)&As[e * 2048 + wave * 512], 16, 0, 0);
            __builtin_amdgcn_global_load_lds(
                (const __attribute__((address_space(1))) void*)&Bw[(size_t)(bn * 128 + row) * C_ + k0 + ks],
                (__attribute__((address_space(3))) void*)&Bs[e * 2048 + wave * 512], 16, 0, 0);
        }
        __syncthreads();
        #pragma unroll
        for (int kk = 0; kk < 64; kk += 32) {
            int o = kk >> 3;                             // 0 or 4
            int xo = ((o + q) ^ xsw) * 8;
            short8 af[4], bfr[4];
            #pragma unroll
            for (int i = 0; i < 4; ++i)
                af[i] = *(const short8*)&As[(wy * 64 + i * 16 + c) * 64 + xo];
            #pragma unroll
            for (int j = 0; j < 4; ++j)
                bfr[j] = *(const short8*)&Bs[(wx * 64 + j * 16 + c) * 64 + xo];
            #pragma unroll
            for (int i = 0; i < 4; ++i)
                #pragma unroll
                for (int j = 0; j < 4; ++j)
                    acc[i][j] = MFMA(af[i], bfr[j], acc[i][j]);
        }
    }
    #pragma unroll
    for (int i = 0; i < 4; ++i)
        #pragma unroll
        for (int j = 0; j < 4; ++j)
            #pragma unroll
            for (int r = 0; r < 4; ++r) {
                int row = bm * 128 + wy * 64 + i * 16 + q * 4 + r;
                int col = bn * 128 + wx * 64 + j * 16 + c;
                if (OUT_FP32) ((float*)Out)[(size_t)row * OC + col] = acc[i][j][r];
                else ((short*)Out)[(size_t)row * OC + col] = f2bf(acc[i][j][r]);
            }
}

// ---------------- k_outer: O_cc = P_cc^T @ P_cc per (b,n,cc), bf16 hi/lo into C slots ----------------
__global__ __launch_bounds__(256) void k_outer(const short* __restrict__ pjqm,
                                               short* __restrict__ Chi, short* __restrict__ Clo) {
    int cc = blockIdx.x, n = blockIdx.y, b = blockIdx.z;   // cc in [0,31): O_31 is never consumed
    int bn = b * NH + n;
    int t = threadIdx.x, wave = t >> 6, lane = t & 63;
    int q = lane >> 4, c = lane & 15;
    __shared__ short Pt_s[64 * 72];   // P_cc^T  [k][v]
    #pragma unroll
    for (int e = 0; e < 2; ++e) {
        int chv = e * 256 + t, row = chv >> 3, sub = chv & 7;   // row = v
        short8 p8 = *(const short8*)&pjqm[(size_t)(b * W_ + cc * 64 + row) * 2048 + n * KH + sub * 8];
        #pragma unroll
        for (int j = 0; j < 8; ++j) Pt_s[(sub * 8 + j) * 72 + row] = p8[j];
    }
    __syncthreads();
    short8 a0 = *(const short8*)&Pt_s[(wave * 16 + c) * 72 + q * 8];
    short8 a1 = *(const short8*)&Pt_s[(wave * 16 + c) * 72 + 32 + q * 8];
    size_t cbase = ((size_t)bn * 32 + cc) * 4096;
    #pragma unroll
    for (int tj = 0; tj < 4; ++tj) {
        short8 b0 = *(const short8*)&Pt_s[(tj * 16 + c) * 72 + q * 8];
        short8 b1 = *(const short8*)&Pt_s[(tj * 16 + c) * 72 + 32 + q * 8];
        f32x4 acc = {};
        acc = MFMA(a0, b0, acc);
        acc = MFMA(a1, b1, acc);
        s16x4 hi, lo;
        #pragma unroll
        for (int r = 0; r < 4; ++r) {
            float a = acc[r];
            short h = f2bf(a);
            hi[r] = h;
            lo[r] = f2bf(a - bf2f(h));
        }
        size_t off = cbase + (size_t)(tj * 16 + c) * 64 + wave * 16 + q * 4;  // [j][k], sym
        *(s16x4*)&Chi[off] = hi;
        *(s16x4*)&Clo[off] = lo;
    }
}

// ---------------- k_scan: in-place exclusive prefix over the 32 chunk slots ----------------
__global__ __launch_bounds__(256) void k_scan(short* __restrict__ Chi, short* __restrict__ Clo) {
    int bn = blockIdx.y;
    int el = blockIdx.x * 1024 + threadIdx.x * 4;
    size_t off = (size_t)bn * 32 * 4096 + el;
    float run[4] = {0.f, 0.f, 0.f, 0.f};
    s16x4 h = *(const s16x4*)&Chi[off];
    s16x4 l = *(const s16x4*)&Clo[off];
    for (int cc = 0; cc < 31; ++cc) {
        s16x4 nh, nl;
        if (cc < 30) {                      // one-deep prefetch of next chunk's O
            nh = *(const s16x4*)&Chi[off + 4096];
            nl = *(const s16x4*)&Clo[off + 4096];
        }
        s16x4 oh, ol;
        #pragma unroll
        for (int r = 0; r < 4; ++r) {
            float o = bf2f(h[r]) + bf2f(l[r]);
            float cv = run[r];
            short hh = f2bf(cv);
            oh[r] = hh;
            ol[r] = f2bf(cv - bf2f(hh));
            run[r] = cv + o;
        }
        *(s16x4*)&Chi[off] = oh;
        *(s16x4*)&Clo[off] = ol;
        h = nh; l = nl;
        off += 4096;
    }
    s16x4 oh, ol;
    #pragma unroll
    for (int r = 0; r < 4; ++r) {
        short hh = f2bf(run[r]);
        oh[r] = hh;
        ol[r] = f2bf(run[r] - bf2f(hh));
    }
    *(s16x4*)&Chi[off] = oh;
    *(s16x4*)&Clo[off] = ol;
}

// ---------------- k_chunk: nudged_c = causal_intra(QM_c,P_c) + QM_c @ (Chi+Clo) ----------------
__global__ __launch_bounds__(256) void k_chunk(const short* __restrict__ pjqm,
                                               const short* __restrict__ Chi, const short* __restrict__ Clo,
                                               short* __restrict__ Nd) {
    int cc = blockIdx.x, n = blockIdx.y, b = blockIdx.z;
    int t = threadIdx.x, wave = t >> 6, lane = t & 63;
    int q = lane >> 4, c = lane & 15;
    __shared__ short Ps[64 * 72];     // P_c   [v][k]
    __shared__ short Pt_s[64 * 72];   // P_c^T [k][v]
    __shared__ short Ch[64 * 72];     // C_hi  [j][k]
    __shared__ short Cl[64 * 72];     // C_lo  [j][k]
    __shared__ short St[4][16 * 72];  // per-wave S strip [w][v]
    int w0g = b * W_ + cc * 64;

    const short* qmrow = &pjqm[(size_t)(w0g + wave * 16 + c) * 2048 + 1024 + n * KH];
    short8 bq0 = *(const short8*)(qmrow + q * 8);
    short8 bq1 = *(const short8*)(qmrow + 32 + q * 8);

    #pragma unroll
    for (int e = 0; e < 2; ++e) {
        int chv = e * 256 + t, row = chv >> 3, sub = chv & 7;
        short8 p8 = *(const short8*)&pjqm[(size_t)(w0g + row) * 2048 + n * KH + sub * 8];
        *(short8*)&Ps[row * 72 + sub * 8] = p8;
        #pragma unroll
        for (int j = 0; j < 8; ++j) Pt_s[(sub * 8 + j) * 72 + row] = p8[j];
        size_t cbase = ((size_t)((b * NH + n) * 32 + cc)) * 4096;
        *(short8*)&Ch[row * 72 + sub * 8] = *(const short8*)&Chi[cbase + row * 64 + sub * 8];
        *(short8*)&Cl[row * 72 + sub * 8] = *(const short8*)&Clo[cbase + row * 64 + sub * 8];
    }
    __syncthreads();
    #pragma unroll
    for (int ct = 0; ct < 4; ++ct) {
        short8 a0 = *(const short8*)&Ps[(ct * 16 + c) * 72 + q * 8];
        short8 a1 = *(const short8*)&Ps[(ct * 16 + c) * 72 + 32 + q * 8];
        f32x4 s = {};
        s = MFMA(a0, bq0, s);
        s = MFMA(a1, bq1, s);
        int vb = ct * 16 + q * 4, wl = wave * 16 + c;
        s16x4 pk;
        #pragma unroll
        for (int r = 0; r < 4; ++r) {
            float v = s[r];
            if (vb + r > wl) v = 0.f;
            pk[r] = f2bf(v);
        }
        *(s16x4*)&St[wave][c * 72 + ct * 16 + q * 4] = pk;
    }
    __syncthreads();
    f32x4 oc[4] = {};
    short8 as0 = *(const short8*)&St[wave][c * 72 + q * 8];
    short8 as1 = *(const short8*)&St[wave][c * 72 + 32 + q * 8];
    #pragma unroll
    for (int tj = 0; tj < 4; ++tj) {
        short8 bp0 = *(const short8*)&Pt_s[(tj * 16 + c) * 72 + q * 8];
        short8 bp1 = *(const short8*)&Pt_s[(tj * 16 + c) * 72 + 32 + q * 8];
        oc[tj] = MFMA(as0, bp0, oc[tj]);
        oc[tj] = MFMA(as1, bp1, oc[tj]);
        short8 bh0 = *(const short8*)&Ch[(tj * 16 + c) * 72 + q * 8];
        short8 bh1 = *(const short8*)&Ch[(tj * 16 + c) * 72 + 32 + q * 8];
        oc[tj] = MFMA(bq0, bh0, oc[tj]);
        oc[tj] = MFMA(bq1, bh1, oc[tj]);
        short8 bl0 = *(const short8*)&Cl[(tj * 16 + c) * 72 + q * 8];
        short8 bl1 = *(const short8*)&Cl[(tj * 16 + c) * 72 + 32 + q * 8];
        oc[tj] = MFMA(bq0, bl0, oc[tj]);
        oc[tj] = MFMA(bq1, bl1, oc[tj]);
    }
    #pragma unroll
    for (int tj = 0; tj < 4; ++tj)
        #pragma unroll
        for (int r = 0; r < 4; ++r)
            Nd[(size_t)(w0g + wave * 16 + q * 4 + r) * C_ + n * KH + tj * 16 + c] = f2bf(oc[tj][r]);
}

extern "C" void kernel_launch(void* const* d_in, const int* in_sizes, int n_in,
                              void* d_out, int out_size, void* d_ws, size_t ws_size,
                              hipStream_t stream) {
    const float* x  = (const float*)d_in[0];
    const float* Wp = (const float*)d_in[1];
    const float* Pm = (const float*)d_in[2];
    const float* Tr = (const float*)d_in[3];
    const float* Wm = (const float*)d_in[4];
    float* out = (float*)d_out;
    char* ws = (char*)d_ws;

    const size_t MB = 1024 * 1024;
    float* metric = (float*)ws;                        // 256 KB
    short* wcat  = (short*)(ws + 256 * 1024);          // 4 MB: [Wp(1024) ; Wq(1024)] x 1024
    short* wp16  = wcat;
    short* wq16  = wcat + C_ * C_;
    short* wf16  = (short*)(ws + 256 * 1024 + 4 * MB); // 2 MB
    short* x16   = (short*)(ws + 256 * 1024 + 6 * MB); // 16 MB (aliased by nd16 later)
    short* pjqm  = (short*)(ws + 256 * 1024 + 22 * MB);// 32 MB: [8192][2048] = [proj | qm]
    short* nd16  = x16;                                // x16 dead after concat GEMM
    short* Chi   = (short*)d_out;                      // d_out as scratch: 16.75 MB
    short* Clo   = Chi + 8 * MB;                       // 16.75 MB (exactly fills d_out)

    k_metric<<<dim3(NH), dim3(256), 0, stream>>>(Pm, metric);
    k_wq<<<dim3(16, NH), dim3(256), 0, stream>>>(metric, Wp, wq16);
    k_wf<<<dim3(16, NH), dim3(256), 0, stream>>>(Tr, Wm, wf16);
    k_cvt<<<dim3(8192), dim3(256), 0, stream>>>(x, x16, (B_ * W_ * C_) / 4);
    k_cvt<<<dim3(1024), dim3(256), 0, stream>>>(Wp, wp16, (C_ * C_) / 4);

    k_gemm256<2048><<<dim3(8, 32), dim3(512), 0, stream>>>(x16, wcat, pjqm);
    k_outer<<<dim3(31, NH, B_), dim3(256), 0, stream>>>(pjqm, Chi, Clo);
    k_scan<<<dim3(4, 64), dim3(256), 0, stream>>>(Chi, Clo);
    k_chunk<<<dim3(32, NH, B_), dim3(256), 0, stream>>>(pjqm, Chi, Clo, nd16);
    k_gemm<1024, true><<<dim3(8, 64), dim3(256), 0, stream>>>(nd16, wf16, (void*)out);
}